// Round 2
// baseline (1531.427 us; speedup 1.0000x reference)
//
#include <hip/hip_runtime.h>
#include <hip/hip_bf16.h>

typedef __attribute__((ext_vector_type(8))) short short8;
typedef __attribute__((ext_vector_type(4))) float f32x4;

__device__ __forceinline__ float bfu2f(unsigned short u) {
    unsigned int x = ((unsigned int)u) << 16;
    float f;
    __builtin_memcpy(&f, &x, 4);
    return f;
}
__device__ __forceinline__ unsigned short f2bfu(float f) {
    unsigned int x;
    __builtin_memcpy(&x, &f, 4);
    unsigned int r = (x + 0x7FFFu + ((x >> 16) & 1u)) >> 16;
    return (unsigned short)r;
}

#define BM 128
#define BN 128
#define BK 32
#define LDA 40  // LDS row stride in bf16 elems (32 + 8 pad, 16B-aligned rows)

// C[M,N] = A[M,K] * B[N,K]^T (bf16 inputs, fp32 accum). A split at k=128
// between Alo/Ahi (both row-stride 128). bias fp32 (optional), relu optional.
// F32OUT selects fp32 vs bf16 output, leading dim N.
template<bool F32OUT>
__global__ __launch_bounds__(256, 2)
void gemm_bt(const unsigned short* __restrict__ Alo,
             const unsigned short* __restrict__ Ahi,
             const unsigned short* __restrict__ B,
             const float* __restrict__ bias,
             void* __restrict__ Cv,
             int M, int N, int K, int relu)
{
    __shared__ unsigned short As[BM * LDA];
    __shared__ unsigned short Bs[BN * LDA];

    const int tid  = threadIdx.x;
    const int m0   = blockIdx.x * BM;
    const int n0   = blockIdx.y * BN;
    const int lane = tid & 63;
    const int wave = tid >> 6;
    const int wr   = wave >> 1;   // wave row (0..1) -> 64 rows
    const int wc   = wave & 1;    // wave col (0..1) -> 64 cols
    const int fm   = lane & 15;   // fragment m/n within 16
    const int fq   = lane >> 4;   // quad (0..3)

    f32x4 acc[4][4] = {};

    for (int k0 = 0; k0 < K; k0 += BK) {
        __syncthreads();
        #pragma unroll
        for (int i = 0; i < 2; ++i) {
            int c  = i * 256 + tid;       // chunk 0..511
            int r  = c >> 2;              // tile row 0..127
            int c8 = (c & 3) << 3;        // col offset {0,8,16,24}
            int ka = k0 + c8;
            uint4 av = make_uint4(0u, 0u, 0u, 0u);
            int grow = m0 + r;
            if (grow < M) {
                const unsigned short* src = (ka < 128)
                    ? (Alo + (size_t)grow * 128 + ka)
                    : (Ahi + (size_t)grow * 128 + (ka - 128));
                av = *(const uint4*)src;
            }
            *(uint4*)(&As[r * LDA + c8]) = av;
            const unsigned short* bsrc = B + (size_t)(n0 + r) * K + ka;
            *(uint4*)(&Bs[r * LDA + c8]) = *(const uint4*)bsrc;
        }
        __syncthreads();

        short8 af[4], bf[4];
        #pragma unroll
        for (int i = 0; i < 4; ++i)
            af[i] = *(const short8*)(&As[(wr * 64 + i * 16 + fm) * LDA + fq * 8]);
        #pragma unroll
        for (int j = 0; j < 4; ++j)
            bf[j] = *(const short8*)(&Bs[(wc * 64 + j * 16 + fm) * LDA + fq * 8]);

        #pragma unroll
        for (int i = 0; i < 4; ++i)
            #pragma unroll
            for (int j = 0; j < 4; ++j)
                acc[i][j] = __builtin_amdgcn_mfma_f32_16x16x32_bf16(
                                af[i], bf[j], acc[i][j], 0, 0, 0);
    }

    // D layout: col = lane&15 (n), row = (lane>>4)*4 + reg (m)
    #pragma unroll
    for (int i = 0; i < 4; ++i) {
        #pragma unroll
        for (int r = 0; r < 4; ++r) {
            int gm = m0 + wr * 64 + i * 16 + fq * 4 + r;
            if (gm < M) {
                #pragma unroll
                for (int j = 0; j < 4; ++j) {
                    int gn = n0 + wc * 64 + j * 16 + fm;
                    float val = acc[i][j][r];
                    if (bias) val += bias[gn];
                    if (relu) val = fmaxf(val, 0.0f);
                    if (F32OUT)
                        ((float*)Cv)[(size_t)gm * N + gn] = val;
                    else
                        ((unsigned short*)Cv)[(size_t)gm * N + gn] = f2bfu(val);
                }
            }
        }
    }
}

// fp32 -> bf16 (4 elems/thread)
__global__ __launch_bounds__(256)
void cvt_k(const float* __restrict__ src, unsigned short* __restrict__ dst, int n4)
{
    int t = blockIdx.x * 256 + threadIdx.x;
    if (t >= n4) return;
    float4 f = ((const float4*)src)[t];
    ushort4 o;
    o.x = f2bfu(f.x); o.y = f2bfu(f.y); o.z = f2bfu(f.z); o.w = f2bfu(f.w);
    ((ushort4*)dst)[t] = o;
}

// hn[u][c] = max(0, max over edges (u,v) of y[v][c]); hn pre-zeroed.
// 32 threads/edge, 4 channels/thread. Non-atomic pre-read filters atomics;
// race-safe: hn monotone non-decreasing, all written values > 0 so signed-int
// ordering == float ordering.
__global__ __launch_bounds__(256)
void scatter_max_k(const int* __restrict__ ei,
                   const unsigned short* __restrict__ y,
                   float* __restrict__ hn, int E)
{
    long long t = (long long)blockIdx.x * 256 + threadIdx.x;
    int e = (int)(t >> 5);
    if (e >= E) return;
    int c = ((int)t & 31) << 2;
    int u = ei[e];
    int v = ei[E + e];
    ushort4 yv = *(const ushort4*)(y + (size_t)v * 128 + c);
    float* hp = hn + (size_t)u * 128 + c;
    float4 cur = *(const float4*)hp;
    float f0 = bfu2f(yv.x), f1 = bfu2f(yv.y), f2 = bfu2f(yv.z), f3 = bfu2f(yv.w);
    if (f0 > cur.x) atomicMax((int*)(hp + 0), __float_as_int(f0));
    if (f1 > cur.y) atomicMax((int*)(hp + 1), __float_as_int(f1));
    if (f2 > cur.z) atomicMax((int*)(hp + 2), __float_as_int(f2));
    if (f3 > cur.w) atomicMax((int*)(hp + 3), __float_as_int(f3));
}

extern "C" void kernel_launch(void* const* d_in, const int* in_sizes, int n_in,
                              void* d_out, int out_size, void* d_ws, size_t ws_size,
                              hipStream_t stream)
{
    const float* x     = (const float*)d_in[0]; // [N,128] f32
    const int*   ei    = (const int*)d_in[1];   // [2,E] int32
    const float* agg_W = (const float*)d_in[2]; // [128,128] f32
    const float* agg_b = (const float*)d_in[3]; // [128] f32
    const float* lin_W = (const float*)d_in[4]; // [1024,256] f32
    float*       out   = (float*)d_out;         // [N,1024] f32

    const int NN = in_sizes[0] / 128;           // 100000
    const int E  = in_sizes[1] / 2;             // 1600000
    const int DI = in_sizes[4] / 256;           // 1024

    char* ws = (char*)d_ws;
    const size_t xN = (size_t)NN * 128;
    unsigned short* xb  = (unsigned short*)ws;                    // 25.6 MB
    unsigned short* y   = (unsigned short*)(ws + xN * 2);         // 25.6 MB (aliased: hnb after scatter)
    float*          hn  = (float*)(ws + xN * 4);                  // 51.2 MB
    unsigned short* awb = (unsigned short*)(ws + xN * 8);         // 32 KB
    unsigned short* lwb = awb + 128 * 128;                        // 512 KB
    unsigned short* hnb = y;                                      // reuse: y dead after scatter

    const int MT = (NN + BM - 1) / BM;          // 782 M-tiles

    // fp32 -> bf16 conversions
    cvt_k<<<((int)(xN / 4) + 255) / 256, 256, 0, stream>>>(x, xb, (int)(xN / 4));
    cvt_k<<<(128 * 128 / 4 + 255) / 256, 256, 0, stream>>>(agg_W, awb, 128 * 128 / 4);
    cvt_k<<<(DI * 256 / 4 + 255) / 256, 256, 0, stream>>>(lin_W, lwb, DI * 256 / 4);

    // hn := 0 (scatter-max identity; also covers nodes with no in-edges)
    hipMemsetAsync(hn, 0, xN * sizeof(float), stream);

    // Stage 1: y = x @ agg_W^T + b (bf16 out; no relu — scatter's 0-floor clamps)
    {
        dim3 grid(MT, 1);
        gemm_bt<false><<<grid, 256, 0, stream>>>(xb, xb, awb, agg_b, y, NN, 128, 128, 0);
    }
    // Stage 2: scatter-max
    {
        long long threads = (long long)E * 32;
        int blocks = (int)((threads + 255) / 256);
        scatter_max_k<<<blocks, 256, 0, stream>>>(ei, y, hn, E);
    }
    // Pack hn -> bf16 (into y's space; y no longer needed)
    cvt_k<<<((int)(xN / 4) + 255) / 256, 256, 0, stream>>>(hn, hnb, (int)(xN / 4));

    // Stage 3: out = relu([x|hn] @ lin_W^T), fp32 out
    {
        dim3 grid(MT, DI / BN);
        gemm_bt<true><<<grid, 256, 0, stream>>>(xb, hnb, lwb, nullptr, out, NN, DI, 256, 1);
    }
}

// Round 3
// 1026.874 us; speedup vs baseline: 1.4913x; 1.4913x over previous
//
#include <hip/hip_runtime.h>
#include <hip/hip_bf16.h>

typedef __attribute__((ext_vector_type(8))) short short8;
typedef __attribute__((ext_vector_type(4))) float f32x4;

__device__ __forceinline__ float bfu2f(unsigned short u) {
    unsigned int x = ((unsigned int)u) << 16;
    float f;
    __builtin_memcpy(&f, &x, 4);
    return f;
}
__device__ __forceinline__ unsigned short f2bfu(float f) {
    unsigned int x;
    __builtin_memcpy(&x, &f, 4);
    unsigned int r = (x + 0x7FFFu + ((x >> 16) & 1u)) >> 16;
    return (unsigned short)r;
}

#define BM 128
#define BN 128
#define BK 32
#define LDA 40  // LDS row stride in bf16 elems (32 + 8 pad, 16B-aligned rows)

// C[M,N] = A[M,K] * B[N,K]^T (bf16 in, fp32 accum). A split at k=128 between
// Alo/Ahi (both row-stride 128). bias fp32 (optional), relu optional.
// F32OUT: fp32 vs bf16 output, leading dim N.
template<bool F32OUT>
__global__ __launch_bounds__(256, 2)
void gemm_bt(const unsigned short* __restrict__ Alo,
             const unsigned short* __restrict__ Ahi,
             const unsigned short* __restrict__ B,
             const float* __restrict__ bias,
             void* __restrict__ Cv,
             int M, int N, int K, int relu)
{
    __shared__ unsigned short As[BM * LDA];
    __shared__ unsigned short Bs[BN * LDA];

    const int tid  = threadIdx.x;
    const int m0   = blockIdx.x * BM;
    const int n0   = blockIdx.y * BN;
    const int lane = tid & 63;
    const int wave = tid >> 6;
    const int wr   = wave >> 1;
    const int wc   = wave & 1;
    const int fm   = lane & 15;
    const int fq   = lane >> 4;

    f32x4 acc[4][4] = {};

    for (int k0 = 0; k0 < K; k0 += BK) {
        __syncthreads();
        #pragma unroll
        for (int i = 0; i < 2; ++i) {
            int c  = i * 256 + tid;
            int r  = c >> 2;
            int c8 = (c & 3) << 3;
            int ka = k0 + c8;
            uint4 av = make_uint4(0u, 0u, 0u, 0u);
            int grow = m0 + r;
            if (grow < M) {
                const unsigned short* src = (ka < 128)
                    ? (Alo + (size_t)grow * 128 + ka)
                    : (Ahi + (size_t)grow * 128 + (ka - 128));
                av = *(const uint4*)src;
            }
            *(uint4*)(&As[r * LDA + c8]) = av;
            const unsigned short* bsrc = B + (size_t)(n0 + r) * K + ka;
            *(uint4*)(&Bs[r * LDA + c8]) = *(const uint4*)bsrc;
        }
        __syncthreads();

        short8 af[4], bf[4];
        #pragma unroll
        for (int i = 0; i < 4; ++i)
            af[i] = *(const short8*)(&As[(wr * 64 + i * 16 + fm) * LDA + fq * 8]);
        #pragma unroll
        for (int j = 0; j < 4; ++j)
            bf[j] = *(const short8*)(&Bs[(wc * 64 + j * 16 + fm) * LDA + fq * 8]);

        #pragma unroll
        for (int i = 0; i < 4; ++i)
            #pragma unroll
            for (int j = 0; j < 4; ++j)
                acc[i][j] = __builtin_amdgcn_mfma_f32_16x16x32_bf16(
                                af[i], bf[j], acc[i][j], 0, 0, 0);
    }

    #pragma unroll
    for (int i = 0; i < 4; ++i) {
        #pragma unroll
        for (int r = 0; r < 4; ++r) {
            int gm = m0 + wr * 64 + i * 16 + fq * 4 + r;
            if (gm < M) {
                #pragma unroll
                for (int j = 0; j < 4; ++j) {
                    int gn = n0 + wc * 64 + j * 16 + fm;
                    float val = acc[i][j][r];
                    if (bias) val += bias[gn];
                    if (relu) val = fmaxf(val, 0.0f);
                    if (F32OUT)
                        ((float*)Cv)[(size_t)gm * N + gn] = val;
                    else
                        ((unsigned short*)Cv)[(size_t)gm * N + gn] = f2bfu(val);
                }
            }
        }
    }
}

// fp32 -> bf16 (4 elems/thread)
__global__ __launch_bounds__(256)
void cvt_k(const float* __restrict__ src, unsigned short* __restrict__ dst, int n4)
{
    int t = blockIdx.x * 256 + threadIdx.x;
    if (t >= n4) return;
    float4 f = ((const float4*)src)[t];
    ushort4 o;
    o.x = f2bfu(f.x); o.y = f2bfu(f.y); o.z = f2bfu(f.z); o.w = f2bfu(f.w);
    ((ushort4*)dst)[t] = o;
}

// CSR build step 1: degree count (deg pre-zeroed)
__global__ __launch_bounds__(256)
void deg_k(const int* __restrict__ ei, int* __restrict__ deg, int E)
{
    int e = blockIdx.x * 256 + threadIdx.x;
    if (e < E) atomicAdd(&deg[ei[e]], 1);
}

// CSR build step 2: exclusive prefix sum (single block, 1024 threads).
// Writes off[0..NN] (off[NN]=E) and a scratch cursor copy.
__global__ __launch_bounds__(1024)
void scan_k(const int* __restrict__ deg, int* __restrict__ off,
            int* __restrict__ cur, int NN)
{
    __shared__ int s[1024];
    int t = threadIdx.x;
    int chunk = (NN + 1023) / 1024;
    int lo = t * chunk;
    int hi = lo + chunk; if (hi > NN) hi = NN; if (lo > NN) lo = NN;
    int sum = 0;
    for (int i = lo; i < hi; ++i) sum += deg[i];
    s[t] = sum;
    __syncthreads();
    for (int ofs = 1; ofs < 1024; ofs <<= 1) {
        int v = (t >= ofs) ? s[t - ofs] : 0;
        __syncthreads();
        s[t] += v;
        __syncthreads();
    }
    int run = (t > 0) ? s[t - 1] : 0;
    for (int i = lo; i < hi; ++i) {
        off[i] = run; cur[i] = run;
        run += deg[i];
    }
    if (t == 1023) off[NN] = s[1023];
}

// CSR build step 3: scatter neighbor ids into adjacency
__global__ __launch_bounds__(256)
void fill_k(const int* __restrict__ ei, int* __restrict__ cur,
            int* __restrict__ adj, int E)
{
    int e = blockIdx.x * 256 + threadIdx.x;
    if (e >= E) return;
    int u = ei[e];
    int v = ei[E + e];
    int pos = atomicAdd(&cur[u], 1);
    adj[pos] = v;
}

// hn[u] = max(0, max over neighbors v of y[v]) — gather form, no atomics.
// 32 lanes per node, 4 channels/lane; acc init 0 implements the relu clamp
// and the empty-neighborhood case. Output bf16 directly.
__global__ __launch_bounds__(256)
void gather_max_k(const int* __restrict__ off, const int* __restrict__ adj,
                  const unsigned short* __restrict__ y,
                  unsigned short* __restrict__ hnb, int NN)
{
    int t = blockIdx.x * 256 + threadIdx.x;
    int u = t >> 5;
    if (u >= NN) return;
    int c = (t & 31) << 2;
    int s = off[u], e2 = off[u + 1];
    float a0 = 0.f, a1 = 0.f, a2 = 0.f, a3 = 0.f;
    int i = s;
    for (; i + 1 < e2; i += 2) {            // 2-wide for load ILP
        int v0 = adj[i], v1 = adj[i + 1];
        ushort4 ya = *(const ushort4*)(y + (size_t)v0 * 128 + c);
        ushort4 yb = *(const ushort4*)(y + (size_t)v1 * 128 + c);
        a0 = fmaxf(a0, fmaxf(bfu2f(ya.x), bfu2f(yb.x)));
        a1 = fmaxf(a1, fmaxf(bfu2f(ya.y), bfu2f(yb.y)));
        a2 = fmaxf(a2, fmaxf(bfu2f(ya.z), bfu2f(yb.z)));
        a3 = fmaxf(a3, fmaxf(bfu2f(ya.w), bfu2f(yb.w)));
    }
    if (i < e2) {
        int v0 = adj[i];
        ushort4 ya = *(const ushort4*)(y + (size_t)v0 * 128 + c);
        a0 = fmaxf(a0, bfu2f(ya.x));
        a1 = fmaxf(a1, bfu2f(ya.y));
        a2 = fmaxf(a2, bfu2f(ya.z));
        a3 = fmaxf(a3, bfu2f(ya.w));
    }
    ushort4 o;
    o.x = f2bfu(a0); o.y = f2bfu(a1); o.z = f2bfu(a2); o.w = f2bfu(a3);
    *(ushort4*)(hnb + (size_t)u * 128 + c) = o;
}

extern "C" void kernel_launch(void* const* d_in, const int* in_sizes, int n_in,
                              void* d_out, int out_size, void* d_ws, size_t ws_size,
                              hipStream_t stream)
{
    const float* x     = (const float*)d_in[0]; // [N,128] f32
    const int*   ei    = (const int*)d_in[1];   // [2,E] int32
    const float* agg_W = (const float*)d_in[2]; // [128,128] f32
    const float* agg_b = (const float*)d_in[3]; // [128] f32
    const float* lin_W = (const float*)d_in[4]; // [1024,256] f32
    float*       out   = (float*)d_out;         // [N,1024] f32

    const int NN = in_sizes[0] / 128;           // 100000
    const int E  = in_sizes[1] / 2;             // 1600000
    const int DI = in_sizes[4] / 256;           // 1024

    char* ws = (char*)d_ws;
    const size_t xN = (size_t)NN * 128;
    unsigned short* xb  = (unsigned short*)ws;                 // 25.6 MB
    unsigned short* y   = xb + xN;                             // 25.6 MB
    unsigned short* hnb = y + xN;                              // 25.6 MB
    unsigned short* awb = hnb + xN;                            // 32 KB
    unsigned short* lwb = awb + 128 * 128;                     // 512 KB
    char* p = (char*)(lwb + (size_t)DI * 256);
    int* deg = (int*)p;                                        // NN ints
    int* off = deg + NN;                                       // NN+1 ints
    int* cur = off + NN + 1;                                   // NN ints
    int* adj = cur + NN;                                       // E ints (6.4 MB)

    const int MT = (NN + BM - 1) / BM;

    // fp32 -> bf16 conversions
    cvt_k<<<((int)(xN / 4) + 255) / 256, 256, 0, stream>>>(x, xb, (int)(xN / 4));
    cvt_k<<<(128 * 128 / 4 + 255) / 256, 256, 0, stream>>>(agg_W, awb, 128 * 128 / 4);
    cvt_k<<<(DI * 256 / 4 + 255) / 256, 256, 0, stream>>>(lin_W, lwb, DI * 256 / 4);

    // Stage 1: y = x @ agg_W^T + b (bf16 out; relu folded into gather's 0-init)
    gemm_bt<false><<<dim3(MT, 1), 256, 0, stream>>>(xb, xb, awb, agg_b, y, NN, 128, 128, 0);

    // CSR build
    hipMemsetAsync(deg, 0, (size_t)NN * sizeof(int), stream);
    deg_k<<<(E + 255) / 256, 256, 0, stream>>>(ei, deg, E);
    scan_k<<<1, 1024, 0, stream>>>(deg, off, cur, NN);
    fill_k<<<(E + 255) / 256, 256, 0, stream>>>(ei, cur, adj, E);

    // Stage 2: gather-max -> hnb (bf16)
    {
        long long threads = (long long)NN * 32;
        int blocks = (int)((threads + 255) / 256);
        gather_max_k<<<blocks, 256, 0, stream>>>(off, adj, y, hnb, NN);
    }

    // Stage 3: out = relu([x|hn] @ lin_W^T), fp32 out
    gemm_bt<true><<<dim3(MT, DI / BN), 256, 0, stream>>>(xb, hnb, lwb, nullptr, out, NN, DI, 256, 1);
}